// Round 8
// baseline (425.468 us; speedup 1.0000x reference)
//
#include <hip/hip_runtime.h>

typedef __attribute__((ext_vector_type(8))) _Float16 half8;
typedef __attribute__((ext_vector_type(4))) _Float16 half4;
typedef __attribute__((ext_vector_type(2))) _Float16 half2;
typedef __attribute__((ext_vector_type(2))) __fp16 fp16x2;
typedef __attribute__((ext_vector_type(4))) float f32x4;

#define N_SEQ 4096
#define HD_QK 96
#define HD_V  64
#define NHEADS 8
// Q pre-scale = (256/8)^-0.5 * log2(e) -> scores in log2 domain
#define QSCALE 0.25505545556f
#define ESHIFT 8.0f
#define NZ 4

union PKC { fp16x2 p; half2 h; };
union H8H2 { half8 v; half2 h2[4]; };

__device__ inline half2 pk_cvt(float a, float b) {
    PKC u;
    u.p = __builtin_amdgcn_cvt_pkrtz(a, b);
    return u.h;
}

__device__ inline half8 cvt8(float4 a, float4 b) {
    half8 h;
    h[0] = (_Float16)a.x; h[1] = (_Float16)a.y; h[2] = (_Float16)a.z; h[3] = (_Float16)a.w;
    h[4] = (_Float16)b.x; h[5] = (_Float16)b.y; h[6] = (_Float16)b.z; h[7] = (_Float16)b.w;
    return h;
}

__device__ inline void cast_blk(const float* __restrict__ in, _Float16* __restrict__ out,
                                int blk, int t) {
    size_t i = ((size_t)blk * 256 + t) * 8;
    float4 a = *(const float4*)(in + i);
    float4 b = *(const float4*)(in + i + 4);
    *(half8*)(out + i) = cvt8(a, b);
}

// ---------------------------------------------------------------------------
// Prep (one launch):
//  [0,1536)     qk -> Xh f16
//  [1536,2560)  v_cls -> Vch f16
//  [2560,3968)  W_qk^T / W_v^T f16
//  [3968,8064)  masks -> swizzled f16 Msw (LDS transpose, coalesced) + Msum
// Msw chunk ((q0b*64+kb)*4 + wsl)*1024 + l15*64 + quad*16 + nt*4 + j
//   holds M[q0b*64 + nt*16 + l15][kb*64 + wsl*16 + quad*4 + j]
// ---------------------------------------------------------------------------
__global__ __launch_bounds__(256) void prep(
    const float* __restrict__ qk, const float* __restrict__ v_cls,
    const float* __restrict__ masks, const float* __restrict__ W_qk,
    const float* __restrict__ W_v,
    _Float16* __restrict__ Xh, _Float16* __restrict__ Vch,
    _Float16* __restrict__ Msw, float* __restrict__ Msum,
    _Float16* __restrict__ Wqkt, _Float16* __restrict__ Wvt)
{
    __shared__ float tile[32][33];
    __shared__ _Float16 Ml[64][68];
    const int bx = blockIdx.x, t = threadIdx.x;
    if (bx < 1536) {
        cast_blk(qk, Xh, bx, t);
    } else if (bx < 2560) {
        cast_blk(v_cls, Vch, bx - 1536, t);
    } else if (bx < 3968) {
        const bool big = bx < 3712;
        const int id = big ? bx - 2560 : bx - 3712;
        const int nx = big ? 48 : 16;
        const int C = big ? 1536 : 512, R = big ? 768 : 512;
        const float* in = big ? W_qk : W_v;
        _Float16* out = big ? Wqkt : Wvt;
        int cx = id % nx, cy = id / nx;
        int tx = t & 31, ty = t >> 5;
        int c0 = cx * 32, r0 = cy * 32;
        for (int k = 0; k < 4; k++)
            tile[ty + 8 * k][tx] = in[(size_t)(r0 + ty + 8 * k) * C + c0 + tx];
        __syncthreads();
        for (int k = 0; k < 4; k++)
            out[(size_t)(c0 + ty + 8 * k) * R + r0 + tx] = (_Float16)tile[tx][ty + 8 * k];
    } else {
        const int b = bx - 3968;                 // [0,4096) : 64x64 mask block
        const int q0b6 = b >> 6, kb = b & 63;
        const int qr = t >> 2, ks = t & 3;
        const float* src = masks + (size_t)(q0b6 * 64 + qr) * N_SEQ + kb * 64 + ks * 16;
        float4 a0 = *(const float4*)src;
        float4 a1 = *(const float4*)(src + 4);
        float4 a2 = *(const float4*)(src + 8);
        float4 a3 = *(const float4*)(src + 12);
        *(half8*)&Ml[qr][ks * 16]     = cvt8(a0, a1);
        *(half8*)&Ml[qr][ks * 16 + 8] = cvt8(a2, a3);
        float s = ((a0.x + a0.y) + (a0.z + a0.w)) + ((a1.x + a1.y) + (a1.z + a1.w))
                + ((a2.x + a2.y) + (a2.z + a2.w)) + ((a3.x + a3.y) + (a3.z + a3.w));
        s += __shfl_xor(s, 1);
        s += __shfl_xor(s, 2);
        if ((t & 3) == 0) atomicAdd(&Msum[q0b6 * 64 + qr], s);
        __syncthreads();
        const int wsl = t >> 6, l15 = (t >> 2) & 15, quad = t & 3;
        _Float16* dst = Msw + ((size_t)(q0b6 * 64 + kb) * 4 + wsl) * 1024
                            + l15 * 64 + quad * 16;
        half8 o0, o1;
        for (int nt = 0; nt < 2; nt++)
            for (int j = 0; j < 4; j++)
                o0[nt * 4 + j] = Ml[nt * 16 + l15][wsl * 16 + quad * 4 + j];
        for (int nt = 2; nt < 4; nt++)
            for (int j = 0; j < 4; j++)
                o1[(nt - 2) * 4 + j] = Ml[nt * 16 + l15][wsl * 16 + quad * 4 + j];
        *(half8*)dst = o0;
        *(half8*)(dst + 8) = o1;
    }
}

// ---------------------------------------------------------------------------
// Fused projection GEMM (f16 in), 64m x 128n tile, BK=64, grid 1024 (4 WG/CU),
// register-prefetch staging (next tile loaded before MFMA section).
// blockIdx.x < 12: Xh@Wqkt^T (N=1536) -> Qh (xQSCALE) / Kh
// else:            Vch@Wvt^T (N=512)  -> Vtg[h][d][n]
// ---------------------------------------------------------------------------
__global__ __launch_bounds__(256, 4) void proj_fused(
    const _Float16* __restrict__ Xh, const _Float16* __restrict__ Vch,
    const _Float16* __restrict__ Wqkt, const _Float16* __restrict__ Wvt,
    _Float16* __restrict__ Qh, _Float16* __restrict__ Kh,
    _Float16* __restrict__ Vtg)
{
    __shared__ _Float16 smem[64 * 72 + 128 * 72];   // 27.6 KB
    _Float16 (*Xs)[72] = (_Float16 (*)[72])smem;
    _Float16 (*Ws)[72] = (_Float16 (*)[72])(smem + 64 * 72);

    const int t = threadIdx.x;
    const int lane = t & 63, wv = t >> 6;
    const int quad = lane >> 4, l15 = lane & 15;
    const bool qkmode = blockIdx.x < 12;
    const int n0 = qkmode ? blockIdx.x * 128 : (blockIdx.x - 12) * 128;
    const int row0 = blockIdx.y * 64;
    const int K = qkmode ? 768 : 512;
    const _Float16* X = qkmode ? Xh : Vch;
    const _Float16* Wt = qkmode ? Wqkt : Wvt;

    const int mB = (wv & 1) * 32, nB = (wv >> 1) * 64;
    const int xr = t >> 2, xc = (t & 3) * 16;
    const int wr = t >> 1, wc = (t & 1) * 32;

    const f32x4 fzero = {0.f, 0.f, 0.f, 0.f};
    f32x4 acc[2][4];
    for (int i = 0; i < 2; i++)
        for (int j = 0; j < 4; j++) acc[i][j] = fzero;

    half8 xg0, xg1, wg0, wg1, wg2, wg3;
    {
        const _Float16* xp = X + (size_t)(row0 + xr) * K + xc;
        xg0 = *(const half8*)xp;
        xg1 = *(const half8*)(xp + 8);
        const _Float16* wp = Wt + (size_t)(n0 + wr) * K + wc;
        wg0 = *(const half8*)wp;
        wg1 = *(const half8*)(wp + 8);
        wg2 = *(const half8*)(wp + 16);
        wg3 = *(const half8*)(wp + 24);
    }

    for (int k0 = 0; k0 < K; k0 += 64) {
        __syncthreads();
        *(half8*)&Xs[xr][xc]     = xg0;
        *(half8*)&Xs[xr][xc + 8] = xg1;
        *(half8*)&Ws[wr][wc]      = wg0;
        *(half8*)&Ws[wr][wc + 8]  = wg1;
        *(half8*)&Ws[wr][wc + 16] = wg2;
        *(half8*)&Ws[wr][wc + 24] = wg3;
        __syncthreads();
        if (k0 + 64 < K) {   // prefetch next tile (latency hidden by MFMAs)
            const _Float16* xp = X + (size_t)(row0 + xr) * K + k0 + 64 + xc;
            xg0 = *(const half8*)xp;
            xg1 = *(const half8*)(xp + 8);
            const _Float16* wp = Wt + (size_t)(n0 + wr) * K + k0 + 64 + wc;
            wg0 = *(const half8*)wp;
            wg1 = *(const half8*)(wp + 8);
            wg2 = *(const half8*)(wp + 16);
            wg3 = *(const half8*)(wp + 24);
        }
        for (int c = 0; c < 2; c++) {
            half8 af[2], bf[4];
            for (int i = 0; i < 2; i++)
                af[i] = *(const half8*)&Xs[mB + 16 * i + l15][c * 32 + quad * 8];
            for (int j = 0; j < 4; j++)
                bf[j] = *(const half8*)&Ws[nB + 16 * j + l15][c * 32 + quad * 8];
            for (int i = 0; i < 2; i++)
                for (int j = 0; j < 4; j++)
                    acc[i][j] = __builtin_amdgcn_mfma_f32_16x16x32_f16(af[i], bf[j], acc[i][j], 0, 0, 0);
        }
    }

    __syncthreads();
    _Float16 (*Ct)[136] = (_Float16 (*)[136])smem;   // 64 x 136
    for (int j = 0; j < 4; j++) {
        int col = n0 + nB + 16 * j + l15;
        float scl = (qkmode && col < 768) ? QSCALE : 1.0f;
        for (int i = 0; i < 2; i++)
            for (int r = 0; r < 4; r++)
                Ct[mB + 16 * i + quad * 4 + r][nB + 16 * j + l15] =
                    (_Float16)(acc[i][j][r] * scl);
    }
    __syncthreads();

    if (qkmode) {
        for (int e = 0; e < 4; e++) {
            int id = e * 256 + t;
            int row = id >> 4, cc = id & 15;
            int col = n0 + cc * 8;
            int w = col >= 768 ? 1 : 0;
            int rem = col - w * 768;
            int h = rem / 96, d = rem - h * 96;
            _Float16* dst = w ? Kh : Qh;
            *(half8*)&dst[((size_t)h * N_SEQ + row0 + row) * HD_QK + d] =
                *(const half8*)&Ct[row][cc * 8];
        }
    } else {
        for (int e = 0; e < 2; e++) {
            int id = e * 256 + t;
            int col = id >> 2, rc = id & 3;
            int c = n0 + col;
            int h = c >> 6, d = c & 63;
            half8 v0, v1;
            for (int k = 0; k < 8; k++) {
                v0[k] = Ct[rc * 16 + k][col];
                v1[k] = Ct[rc * 16 + 8 + k][col];
            }
            _Float16* dst = &Vtg[((size_t)h * HD_V + d) * N_SEQ + row0 + rc * 16];
            *(half8*)dst = v0;
            *(half8*)(dst + 8) = v1;
        }
    }
}

// ---------------------------------------------------------------------------
// Flash attention: key-sliced waves, split-K z=4 (grid 2048 = 2 exact rounds
// at 4 WG/CU, reg cap 128), q0-major XCD pinning. Swizzled f16 masks.
// p = exp2(s'-8) exact shift; partials (O f16, l f32) to ws.
// ---------------------------------------------------------------------------
__global__ __launch_bounds__(256, 4) void flash_attn(
    const _Float16* __restrict__ Qh, const _Float16* __restrict__ Kh,
    const _Float16* __restrict__ Vtg, const _Float16* __restrict__ Msw,
    _Float16* __restrict__ Owsh, float* __restrict__ Lws)
{
    __shared__ __align__(16) float Ob[2][64][68];
    __shared__ float Lb[2][64];

    const int t = threadIdx.x;
    const int lane = t & 63, w = t >> 6;
    const int quad = lane >> 4, l15 = lane & 15;
    const int bx = blockIdx.x;
    const int q0b = bx & 63;
    const int hz = bx >> 6;
    const int head = hz & 7;
    const int z = hz >> 3;
    const int q0 = q0b * 64;
    const int kb0 = 16 * z, kbE = kb0 + 16;

    half8 qf[3][4];
    for (int nt = 0; nt < 4; nt++) {
        const _Float16* qp = Qh + ((size_t)head * N_SEQ + q0 + 16 * nt + l15) * HD_QK + 8 * quad;
        for (int c = 0; c < 3; c++)
            qf[c][nt] = *(const half8*)(qp + 32 * c);
    }

    const _Float16* kbase = Kh + ((size_t)head * N_SEQ + 16 * w + l15) * HD_QK + 8 * quad;
    const _Float16* vbase = Vtg + ((size_t)head * HD_V + l15) * N_SEQ + 16 * w + 4 * quad;
    const _Float16* mbase = Msw + ((size_t)(q0b * 64 + kb0) * 4 + w) * 1024
                                + (l15 * 4 + quad) * 16;

    const f32x4 fzero = {0.f, 0.f, 0.f, 0.f};
    f32x4 oacc[4][4];
    for (int nt = 0; nt < 4; nt++)
        for (int v = 0; v < 4; v++) oacc[nt][v] = fzero;
    float lsum[4] = {0.f, 0.f, 0.f, 0.f};

    half8 kf[3];
    half4 vf[4];
    H8H2 mu0, mu1;
    {
        const _Float16* kp = kbase + (size_t)kb0 * 64 * HD_QK;
        for (int c = 0; c < 3; c++) kf[c] = *(const half8*)(kp + 32 * c);
        const _Float16* vp = vbase + kb0 * 64;
        for (int v = 0; v < 4; v++) vf[v] = *(const half4*)(vp + (size_t)(16 * v) * N_SEQ);
        mu0.v = *(const half8*)mbase;
        mu1.v = *(const half8*)(mbase + 8);
    }

    for (int kb = kb0; kb < kbE; kb++) {
        const int kn = (kb + 1 < kbE) ? kb + 1 : kb;

        // S^T = K Q^T
        f32x4 sT[4];
        for (int nt = 0; nt < 4; nt++) sT[nt] = fzero;
        for (int c = 0; c < 3; c++)
            for (int nt = 0; nt < 4; nt++)
                sT[nt] = __builtin_amdgcn_mfma_f32_16x16x32_f16(kf[c], qf[c][nt], sT[nt], 0, 0, 0);
        {
            const _Float16* kp = kbase + (size_t)kn * 64 * HD_QK;
            for (int c = 0; c < 3; c++) kf[c] = *(const half8*)(kp + 32 * c);
        }

        // p = exp2(s-8); lsum; af = f16(p) * mask (packed, mask via bit-cast)
        half4 af[4];
        for (int nt = 0; nt < 4; nt++) {
            const half2* mh = (nt < 2) ? mu0.h2 : mu1.h2;
            const int mb = (nt & 1) * 2;
            float p0 = exp2f(sT[nt][0] - ESHIFT);
            float p1 = exp2f(sT[nt][1] - ESHIFT);
            float p2 = exp2f(sT[nt][2] - ESHIFT);
            float p3 = exp2f(sT[nt][3] - ESHIFT);
            lsum[nt] += (p0 + p1) + (p2 + p3);
            half2 lo = pk_cvt(p0, p1) * mh[mb];
            half2 hi = pk_cvt(p2, p3) * mh[mb + 1];
            af[nt] = half4{lo[0], lo[1], hi[0], hi[1]};
        }
        {
            const _Float16* mp = mbase + (size_t)(kn - kb0) * 4096;
            mu0.v = *(const half8*)mp;
            mu1.v = *(const half8*)(mp + 8);
        }

        // O += P V
        for (int nt = 0; nt < 4; nt++)
            for (int v = 0; v < 4; v++)
                oacc[nt][v] = __builtin_amdgcn_mfma_f32_16x16x16f16(af[nt], vf[v], oacc[nt][v], 0, 0, 0);
        {
            const _Float16* vp = vbase + kn * 64;
            for (int v = 0; v < 4; v++) vf[v] = *(const half4*)(vp + (size_t)(16 * v) * N_SEQ);
        }
    }

    for (int nt = 0; nt < 4; nt++) {
        lsum[nt] += __shfl_xor(lsum[nt], 16);
        lsum[nt] += __shfl_xor(lsum[nt], 32);
    }

    if (w & 1) {
        for (int nt = 0; nt < 4; nt++) {
            for (int v = 0; v < 4; v++)
                for (int r = 0; r < 4; r++)
                    Ob[w >> 1][16 * nt + 4 * quad + r][16 * v + l15] = oacc[nt][v][r];
            if (quad == 0) Lb[w >> 1][16 * nt + l15] = lsum[nt];
        }
    }
    __syncthreads();
    if (!(w & 1)) {
        for (int nt = 0; nt < 4; nt++) {
            for (int v = 0; v < 4; v++)
                for (int r = 0; r < 4; r++)
                    Ob[w >> 1][16 * nt + 4 * quad + r][16 * v + l15] += oacc[nt][v][r];
            if (quad == 0) Lb[w >> 1][16 * nt + l15] += lsum[nt];
        }
    }
    __syncthreads();

    {
        int row = t >> 2, c0 = (t & 3) * 16;
        _Float16* obase = Owsh + (size_t)z * N_SEQ * 512 + (size_t)(q0 + row) * 512
                          + head * HD_V + c0;
        for (int g = 0; g < 2; g++) {
            half8 h;
            for (int j = 0; j < 8; j++)
                h[j] = (_Float16)(Ob[0][row][c0 + 8 * g + j] + Ob[1][row][c0 + 8 * g + j]);
            *(half8*)(obase + 8 * g) = h;
        }
        if (t < 64)
            Lws[((size_t)z * NHEADS + head) * N_SEQ + q0 + t] = Lb[0][t] + Lb[1][t];
    }
}

// ---------------------------------------------------------------------------
// Finalize: out = sum_z O_z / (sum_z l_z * H * Msum[q])
// ---------------------------------------------------------------------------
__global__ __launch_bounds__(256) void finalize(
    const _Float16* __restrict__ Owsh, const float* __restrict__ Lws,
    const float* __restrict__ Msum, float* __restrict__ out)
{
    const size_t ZSTR = (size_t)N_SEQ * 512;
    size_t o = ((size_t)blockIdx.x * 256 + threadIdx.x) * 8;
    int q = (int)(o >> 9);
    int head = (int)((o & 511) >> 6);
    float l = 0.f;
    for (int z = 0; z < NZ; z++)
        l += Lws[((size_t)z * NHEADS + head) * N_SEQ + q];
    float inv = 1.0f / (l * (float)NHEADS * Msum[q]);
    float acc[8];
    for (int j = 0; j < 8; j++) acc[j] = 0.f;
    for (int z = 0; z < NZ; z++) {
        half8 p = *(const half8*)(Owsh + (size_t)z * ZSTR + o);
        for (int j = 0; j < 8; j++) acc[j] += (float)p[j];
    }
    float4 r0 = {acc[0] * inv, acc[1] * inv, acc[2] * inv, acc[3] * inv};
    float4 r1 = {acc[4] * inv, acc[5] * inv, acc[6] * inv, acc[7] * inv};
    *(float4*)(out + o) = r0;
    *(float4*)(out + o + 4) = r1;
}

extern "C" void kernel_launch(void* const* d_in, const int* in_sizes, int n_in,
                              void* d_out, int out_size, void* d_ws, size_t ws_size,
                              hipStream_t stream) {
    const float* qk    = (const float*)d_in[0];
    const float* v_cls = (const float*)d_in[1];
    const float* masks = (const float*)d_in[2];
    const float* W_qk  = (const float*)d_in[3];
    const float* W_v   = (const float*)d_in[4];
    float* out = (float*)d_out;

    char* wsp = (char*)d_ws;
    // region0 [0, 16.78 MB): prep/proj-stage buffers, later aliased by Owsh
    _Float16* Xh   = (_Float16*)(wsp);                         // 6.29 MB
    _Float16* Vch  = (_Float16*)(wsp + (size_t)6291456);       // 4.19 MB
    _Float16* Wqkt = (_Float16*)(wsp + (size_t)10485760);      // 2.36 MB
    _Float16* Wvt  = (_Float16*)(wsp + (size_t)12845056);      // 0.52 MB
    _Float16* Owsh = (_Float16*)(wsp);                         // 4*4096*512*2 = 16.78 MB
    size_t off = 16777216;
    auto allocB = [&](size_t bytes) { char* p = wsp + off; off += (bytes + 255) & ~(size_t)255; return p; };
    _Float16* Qh   = (_Float16*)allocB((size_t)NHEADS * N_SEQ * HD_QK * 2);
    _Float16* Kh   = (_Float16*)allocB((size_t)NHEADS * N_SEQ * HD_QK * 2);
    _Float16* Vtg  = (_Float16*)allocB((size_t)NHEADS * HD_V * N_SEQ * 2);
    _Float16* Msw  = (_Float16*)allocB((size_t)N_SEQ * N_SEQ * 2);
    float*    Msum = (float*)allocB((size_t)N_SEQ * 4);
    float*    Lws  = (float*)allocB((size_t)NZ * NHEADS * N_SEQ * 4);
    (void)ws_size;

    dim3 blk(256);
    (void)hipMemsetAsync(Msum, 0, N_SEQ * sizeof(float), stream);
    prep<<<dim3(8064), blk, 0, stream>>>(
        qk, v_cls, masks, W_qk, W_v, Xh, Vch, Msw, Msum, Wqkt, Wvt);

    proj_fused<<<dim3(16, N_SEQ / 64), blk, 0, stream>>>(
        Xh, Vch, Wqkt, Wvt, Qh, Kh, Vtg);

    flash_attn<<<dim3(64 * NHEADS * NZ), blk, 0, stream>>>(
        Qh, Kh, Vtg, Msw, Owsh, Lws);

    finalize<<<dim3((N_SEQ * 512) / (256 * 8)), blk, 0, stream>>>(
        Owsh, Lws, Msum, out);
}